// Round 7
// baseline (321.087 us; speedup 1.0000x reference)
//
#include <hip/hip_runtime.h>

// FlowNet correlation, kernel_size=1, max_disp=4.
// out[b, (dy+4)*9+(dx+4), y, x] = (1/C) * sum_c in1[b,c,y,x]*in2[b,c,y+dy,x+dx]
//
// R7 = R6 + (1) in1 chunk-hoist + (2) XCD-chunked block swizzle.
// R6 diagnosis: latency-bound (no pipe >45%); the compute loop had 8
// serially-dependent in1 global loads per chunk (load k -> FMA k -> load
// k+1...). Hoisting all 8 loads to the chunk head makes them issue
// back-to-back: one exposed memory latency per chunk instead of eight.
// The in2 halo re-reads (2.5x) missed L2 because y-neighbor blocks were 10
// dispatch ids apart (different XCD under round-robin); chunked swizzle
// (T1) puts 200 consecutive ids on one XCD -> halo rows hit that XCD's L2.
// Tile 8x32, 9 waves (wave = dy), 576 thr; acc[9][4]=36 regs; in2 staged
// in one 22.5 KB LDS buffer with reg-prefetch double-buffering (R6).

#define BB 8
#define CC 96
#define HH 160
#define WW 320
#define TY 8
#define TX 32
#define CK 8
#define NCH (CC / CK)            // 12
#define HR (TY + 8)              // 16 halo rows
#define SW 44                    // LDS row stride floats (11 f4: 10 data + 1 pad)
#define NT 576
#define HW (HH * WW)
#define NSLOT (CK * HR * (SW / 4))   // 1408 f4 slots
#define NSTG 3                       // ceil(1408/576)
#define NWG (BB * (HH / TY) * (WW / TX))  // 1600
#define NXCD 8
#define CPX (NWG / NXCD)             // 200

__global__ __launch_bounds__(NT, 2)
void corr_kernel(const float* __restrict__ in1,
                 const float* __restrict__ in2,
                 float* __restrict__ out) {
    // ---- XCD-chunked swizzle: consecutive 200 ids -> one XCD ----
    const int bid  = blockIdx.x;
    const int nid  = (bid % NXCD) * CPX + bid / NXCD;
    const int bz   = nid / ((HH / TY) * (WW / TX));
    const int rem0 = nid % ((HH / TY) * (WW / TX));
    const int by   = rem0 / (WW / TX);
    const int bx   = rem0 % (WW / TX);

    const int x0 = bx * TX;
    const int y0 = by * TY;
    const int b  = bz;

    const int tid  = threadIdx.x;
    const int dy   = tid >> 6;       // 0..8, uniform per wave
    const int lane = tid & 63;
    const int yi   = lane >> 3;      // 0..7 output row in tile
    const int xt   = lane & 7;       // 0..7 -> 4-pixel x sub-block

    __shared__ __align__(16) float s2[CK][HR][SW];

    // ---- staging descriptors (once): f4-slot i = tid + t*NT ----
    int goff[NSTG];
    float4* lsl[NSTG];
    bool ok[NSTG];
#pragma unroll
    for (int t = 0; t < NSTG; ++t) {
        const int i = tid + t * NT;
        ok[t] = false; goff[t] = 0; lsl[t] = (float4*)&s2[0][0][0];
        if (i < NSLOT) {
            const int k = i / (HR * 11), rem = i % (HR * 11);
            const int r = rem / 11, c4 = rem % 11;
            lsl[t] = (float4*)&s2[k][r][4 * c4];
            const int yy = y0 + r - 4;
            const int xs = x0 - 4 + 4 * c4;
            if (c4 < 10 && (unsigned)yy < (unsigned)HH &&
                (unsigned)xs <= (unsigned)(WW - 4)) {
                ok[t] = true;
                goff[t] = (k * HH + yy) * WW + xs;
            }
        }
    }

    // ---- zero LDS once: OOB/pad slots stay zero across all chunks ----
    {
        const float4 z = make_float4(0.f, 0.f, 0.f, 0.f);
        float4* p0 = (float4*)&s2[0][0][0];
        for (int i = tid; i < NSLOT; i += NT) p0[i] = z;
    }

    float acc[9][4];
#pragma unroll
    for (int i = 0; i < 9; ++i)
#pragma unroll
        for (int j = 0; j < 4; ++j) acc[i][j] = 0.0f;

    const float* in1p = in1 + ((size_t)(b * CC) * HH + y0 + yi) * WW + x0 + 4 * xt;

    // ---- prologue: prefetch chunk 0 of in2 into registers ----
    const float4 z4 = make_float4(0.f, 0.f, 0.f, 0.f);
    float4 p[NSTG];
    {
        const int cb = (b * CC) * HW;
#pragma unroll
        for (int t = 0; t < NSTG; ++t)
            p[t] = ok[t] ? *(const float4*)(in2 + cb + goff[t]) : z4;
    }

    for (int ch = 0; ch < NCH; ++ch) {
        __syncthreads();                     // all readers of prev chunk done
#pragma unroll
        for (int t = 0; t < NSTG; ++t)
            if (ok[t]) *lsl[t] = p[t];       // ds_write prefetched chunk
        __syncthreads();                     // chunk visible

        if (ch + 1 < NCH) {                  // issue next in2 loads; latency
            const int cb = (b * CC + (ch + 1) * CK) * HW;  // hides under FMAs
#pragma unroll
            for (int t = 0; t < NSTG; ++t)
                if (ok[t]) p[t] = *(const float4*)(in2 + cb + goff[t]);
        }

        // ---- hoisted in1 loads: 8 issued back-to-back, one latency ----
        float a[CK][4];
#pragma unroll
        for (int k = 0; k < CK; ++k)
            *(float4*)a[k] = *(const float4*)(in1p + (size_t)(ch * CK + k) * HW);

#pragma unroll
        for (int k = 0; k < CK; ++k) {
            float v[12];
#pragma unroll
            for (int q = 0; q < 3; ++q)
                *(float4*)&v[4 * q] = *(const float4*)&s2[k][yi + dy][4 * xt + 4 * q];
#pragma unroll
            for (int dxi = 0; dxi < 9; ++dxi)
#pragma unroll
                for (int xi = 0; xi < 4; ++xi)
                    acc[dxi][xi] = fmaf(a[k][xi], v[xi + dxi], acc[dxi][xi]);
        }
    }

    // ---- epilogue: scale by 1/C, one float4 store per dx ----
    const float scale = 1.0f / (float)CC;
#pragma unroll
    for (int dxi = 0; dxi < 9; ++dxi) {
        float4 o = make_float4(acc[dxi][0] * scale, acc[dxi][1] * scale,
                               acc[dxi][2] * scale, acc[dxi][3] * scale);
        float* dst = out +
            (((size_t)(b * 81 + dy * 9 + dxi) * HH + y0 + yi) * WW + x0 + 4 * xt);
        *(float4*)dst = o;
    }
}

extern "C" void kernel_launch(void* const* d_in, const int* in_sizes, int n_in,
                              void* d_out, int out_size, void* d_ws, size_t ws_size,
                              hipStream_t stream) {
    const float* in1 = (const float*)d_in[0];
    const float* in2 = (const float*)d_in[1];
    float* out = (float*)d_out;
    corr_kernel<<<dim3(NWG), dim3(NT), 0, stream>>>(in1, in2, out);
}

// Round 8
// 316.104 us; speedup vs baseline: 1.0158x; 1.0158x over previous
//
#include <hip/hip_runtime.h>

// FlowNet correlation, kernel_size=1, max_disp=4.
// out[b, (dy+4)*9+(dx+4), y, x] = (1/C) * sum_c in1[b,c,y,x]*in2[b,c,y+dy,x+dx]
//
// R8: occupancy restructure. R1-R7 all used 9-wave (576-thr) blocks at
// ~100-110 unified regs/wave -> 4-wave/SIMD bracket -> exactly ONE block
// resident per CU (two blocks would need 5 waves on a SIMD). All latency
// exposed; VALUBusy pinned at 18%, occupancy at 24% across 7 variants.
// Fix: 3-wave blocks (192 thr) -- wave = dy within a group g of 3 dy
// values, grid x3. ~80 regs/wave -> 5-6 waves/SIMD -> 5+ independent
// blocks/CU; cross-block TLP hides staging latency (m114), so the loop is
// the plain stage/sync/compute/sync with no reg-prefetch.
// Sibling g-blocks are id-adjacent under the chunked XCD swizzle -> in1
// tile + in2 halo rows shared in the XCD's L2 (mechanism verified in R7:
// FETCH 440->181 MB).
// Thread = 4 px, acc[9 dx][4 px] = 36 regs. in2 staged per-group: 10 halo
// rows x CK channels, row stride 44 floats; OOB/pad slots zeroed once.

#define BB 8
#define CC 96
#define HH 160
#define WW 320
#define TY 8
#define TX 32
#define GG 3                 // dy-group size (waves per block)
#define CK 8
#define NCH (CC / CK)        // 12
#define HRG 10               // halo rows per group: 8 + (GG-1) + ... = 10
#define SW 44                // LDS row stride floats (11 f4: 10 data + 1 pad)
#define NT (GG * 64)         // 192
#define HW (HH * WW)
#define NSLOT (CK * HRG * 11)    // 880 f4 slots
#define NSTG 5                   // ceil(880/192)
#define NBX (WW / TX)            // 10
#define NBY (HH / TY)            // 20
#define NWG (BB * NBY * NBX * 3) // 4800
#define NXCD 8
#define CPX (NWG / NXCD)         // 600

__global__ __launch_bounds__(NT, 5)
void corr_kernel(const float* __restrict__ in1,
                 const float* __restrict__ in2,
                 float* __restrict__ out) {
    // ---- chunked XCD swizzle; g fastest so siblings share an XCD L2 ----
    const int bid = blockIdx.x;
    const int nid = (bid % NXCD) * CPX + bid / NXCD;
    const int g   = nid % 3;
    int t         = nid / 3;
    const int bx  = t % NBX;  t /= NBX;
    const int by  = t % NBY;
    const int b   = t / NBY;

    const int x0 = bx * TX;
    const int y0 = by * TY;

    const int tid  = threadIdx.x;
    const int wv   = tid >> 6;       // 0..2, uniform per wave
    const int lane = tid & 63;
    const int yi   = lane >> 3;      // 0..7 output row in tile
    const int xt   = lane & 7;       // 0..7 -> 4-pixel x sub-block
    const int dyi  = 3 * g + wv;     // 0..8 = dy+4

    __shared__ __align__(16) float s2[CK][HRG][SW];

    // ---- staging descriptors (once): f4-slot i = tid + t*NT ----
    // s2 row r <-> global row y0 + 3g - 4 + r
    int goff[NSTG];
    float4* lsl[NSTG];
    bool ok[NSTG];
#pragma unroll
    for (int s = 0; s < NSTG; ++s) {
        const int i = tid + s * NT;
        ok[s] = false; goff[s] = 0; lsl[s] = (float4*)&s2[0][0][0];
        if (i < NSLOT) {
            const int k = i / (HRG * 11), rem = i % (HRG * 11);
            const int r = rem / 11, c4 = rem % 11;
            lsl[s] = (float4*)&s2[k][r][4 * c4];
            const int yy = y0 + 3 * g - 4 + r;
            const int xs = x0 - 4 + 4 * c4;
            if (c4 < 10 && (unsigned)yy < (unsigned)HH &&
                (unsigned)xs <= (unsigned)(WW - 4)) {
                ok[s] = true;
                goff[s] = (k * HH + yy) * WW + xs;
            }
        }
    }

    // ---- zero LDS once: OOB/pad slots stay zero across all chunks ----
    {
        const float4 z = make_float4(0.f, 0.f, 0.f, 0.f);
        float4* p0 = (float4*)&s2[0][0][0];
        for (int i = tid; i < NSLOT; i += NT) p0[i] = z;
    }

    float acc[9][4];
#pragma unroll
    for (int i = 0; i < 9; ++i)
#pragma unroll
        for (int j = 0; j < 4; ++j) acc[i][j] = 0.0f;

    const float* in1p = in1 + ((size_t)(b * CC) * HH + y0 + yi) * WW + x0 + 4 * xt;

    for (int ch = 0; ch < NCH; ++ch) {
        const int cb = (b * CC + ch * CK) * HW;
        __syncthreads();                     // readers of prev chunk done
#pragma unroll
        for (int s = 0; s < NSTG; ++s)
            if (ok[s]) *lsl[s] = *(const float4*)(in2 + cb + goff[s]);
        __syncthreads();                     // chunk visible

#pragma unroll
        for (int k = 0; k < CK; ++k) {
            float a[4];
            *(float4*)a = *(const float4*)(in1p + (size_t)(ch * CK + k) * HW);
            float v[12];
#pragma unroll
            for (int q = 0; q < 3; ++q)
                *(float4*)&v[4 * q] =
                    *(const float4*)&s2[k][yi + wv][4 * xt + 4 * q];
#pragma unroll
            for (int dxi = 0; dxi < 9; ++dxi)
#pragma unroll
                for (int xi = 0; xi < 4; ++xi)
                    acc[dxi][xi] = fmaf(a[xi], v[xi + dxi], acc[dxi][xi]);
        }
    }

    // ---- epilogue: scale by 1/C, one float4 store per dx ----
    const float scale = 1.0f / (float)CC;
#pragma unroll
    for (int dxi = 0; dxi < 9; ++dxi) {
        float4 o = make_float4(acc[dxi][0] * scale, acc[dxi][1] * scale,
                               acc[dxi][2] * scale, acc[dxi][3] * scale);
        float* dst = out +
            (((size_t)(b * 81 + dyi * 9 + dxi) * HH + y0 + yi) * WW + x0 + 4 * xt);
        *(float4*)dst = o;
    }
}

extern "C" void kernel_launch(void* const* d_in, const int* in_sizes, int n_in,
                              void* d_out, int out_size, void* d_ws, size_t ws_size,
                              hipStream_t stream) {
    const float* in1 = (const float*)d_in[0];
    const float* in2 = (const float*)d_in[1];
    float* out = (float*)d_out;
    corr_kernel<<<dim3(NWG), dim3(NT), 0, stream>>>(in1, in2, out);
}